// Round 6
// baseline (384.804 us; speedup 1.0000x reference)
//
#include <hip/hip_runtime.h>

// NNConvCritic on MI355X (gfx950).
// R6: occupancy + dispatch-count attack.
//  - edge_kernel: __launch_bounds__(256,4), grid 1024 -> 4 blocks/CU resident
//    (LDS 38400B x4 = 153.6KB < 160KB), inter-block overlap hides barriers.
//  - 8 dispatches -> 4: setup (prep|xconv|stats partitioned by blockIdx),
//    mid (block 64: stats-reduce + BN coeffs; blocks 0..63: sumx), edge,
//    critic.
// Per-graph accumulation stays native ds_add_u32 fixed-point (R5 win).

#define E_EDGES   800000
#define N_NODES   50000
#define G_GRAPHS  64
#define EDGE_GRID 1024
#define STAT_GRID 512
#define NIT       (E_EDGES / 64)   // 12500
#define QSCALE    131072.0f        // 2^17
#define QINV      (1.0f / 131072.0f)

typedef _Float16 f16x2 __attribute__((ext_vector_type(2)));
typedef _Float16 f16x8 __attribute__((ext_vector_type(8)));
typedef __fp16   fp16x2 __attribute__((ext_vector_type(2)));
typedef float    f32x4 __attribute__((ext_vector_type(4)));
typedef unsigned u32x4 __attribute__((ext_vector_type(4)));

union H2U { f16x2 h; unsigned u; };
union F8U { f16x8 v; f16x2 h2[4]; u32x4 u4; };

__device__ __forceinline__ f16x2 pkrtz(float a, float b) {
  fp16x2 r = __builtin_amdgcn_cvt_pkrtz(a, b);
  return __builtin_bit_cast(f16x2, r);
}

// ---------------------------------------------------------------------------
// setup: blocks [0,512) stats | [512,582) prep | [582,2145) xconv.
// stats: S = EA^T EA + col sums via MFMA(a,a); block partials -> gstatsT
//        [v(272)][block(512)] (transposed for the reduce).
// prep:  f16 B-fragment tables. Bbuf [s(0..32)][nt(0..1)][lane][r]
//        (s<32: W2' K-slices; s==32: b2 row-trick). Bw1 [nt(0..3)][lane][r].
// xconv: x f32 -> packed f16 pairs.
// ---------------------------------------------------------------------------
__global__ __launch_bounds__(256) void setup_kernel(
    const float* __restrict__ W2, const float* __restrict__ b2,
    const float* __restrict__ W1, const float* __restrict__ x,
    const float* __restrict__ ea, unsigned* __restrict__ Bbuf,
    unsigned* __restrict__ Bw1, unsigned* __restrict__ xh,
    float* __restrict__ gstatsT)
{
  __shared__ float red[4][272];
  const int b = blockIdx.x, tid = threadIdx.x;
  if (b < STAT_GRID) {
    int lane = tid & 63, wave = tid >> 6;
    int nl = lane & 15, q = lane >> 4;
    int gw = b * 4 + wave;
    f32x4 acc = (f32x4){0.f, 0.f, 0.f, 0.f};
    float ms = 0.f;
    for (int c0 = gw; c0 < E_EDGES / 32; c0 += STAT_GRID * 4) {
      const float* p = ea + (size_t)(c0 * 32 + q * 8) * 16 + nl;
      float v0 = p[0],  v1 = p[16], v2 = p[32], v3 = p[48];
      float v4 = p[64], v5 = p[80], v6 = p[96], v7 = p[112];
      ms += (v0 + v1) + (v2 + v3) + (v4 + v5) + (v6 + v7);
      F8U av;
      av.h2[0] = pkrtz(v0, v1); av.h2[1] = pkrtz(v2, v3);
      av.h2[2] = pkrtz(v4, v5); av.h2[3] = pkrtz(v6, v7);
      acc = __builtin_amdgcn_mfma_f32_16x16x32_f16(av.v, av.v, acc, 0, 0, 0);
    }
    ms += __shfl_xor(ms, 16, 64);
    ms += __shfl_xor(ms, 32, 64);
#pragma unroll
    for (int r = 0; r < 4; ++r) red[wave][(q * 4 + r) * 16 + nl] = acc[r];
    if (q == 0) red[wave][256 + nl] = ms;
    __syncthreads();
    for (int v = tid; v < 272; v += 256)
      gstatsT[(size_t)v * STAT_GRID + b] =
          red[0][v] + red[1][v] + red[2][v] + red[3][v];
  } else if (b < STAT_GRID + 70) {
    int idx = (b - STAT_GRID) * 256 + tid;  // [0, 17920) = 16896 + 1024
    if (idx < 33 * 512) {
      int r = idx & 3, lane = (idx >> 2) & 63, nt = (idx >> 8) & 1,
          s = idx >> 9;
      int q = lane >> 4, nl = lane & 15, n = nt * 16 + nl;
      float v0 = 0.f, v1 = 0.f;
      if (n < 20) {
        if (s < 32) {
          int K0 = s * 32 + q * 8 + 2 * r;
          v0 = W2[(K0 >> 4) * 320 + (K0 & 15) * 20 + n];
          v1 = W2[((K0 + 1) >> 4) * 320 + ((K0 + 1) & 15) * 20 + n];
        } else if (q < 2) {
          int i0 = q * 8 + 2 * r;
          v0 = b2[i0 * 20 + n];
          v1 = b2[(i0 + 1) * 20 + n];
        }
      }
      H2U pk; pk.h = pkrtz(v0, v1);
      Bbuf[idx] = pk.u;
    } else {
      int idx2 = idx - 33 * 512;  // [0,1024)
      int r = idx2 & 3, lane = (idx2 >> 2) & 63, nt = idx2 >> 8;
      int q = lane >> 4, nl = lane & 15, n = nt * 16 + nl;
      int k0 = q * 8 + 2 * r;
      float v0 = (k0 < 16)     ? W1[k0 * 64 + n]       : 0.f;
      float v1 = (k0 + 1 < 16) ? W1[(k0 + 1) * 64 + n] : 0.f;
      H2U pk; pk.h = pkrtz(v0, v1);
      Bw1[idx2] = pk.u;
    }
  } else {
    int i = (b - STAT_GRID - 70) * 256 + tid;
    if (i < N_NODES * 8) {
      H2U pk; pk.h = pkrtz(x[2 * i], x[2 * i + 1]);
      xh[i] = pk.u;
    }
  }
}

// ---------------------------------------------------------------------------
// mid: block 64 = stats reduce (coalesced-per-thread rows of gstatsT) + BN
// scale/shift (folds b1). blocks 0..63 = per-graph x column sums + counts.
// ---------------------------------------------------------------------------
__global__ __launch_bounds__(256) void mid_kernel(
    const float* __restrict__ gstatsT, const float* __restrict__ W1,
    const float* __restrict__ b1, const float* __restrict__ gamma,
    const float* __restrict__ beta, const float* __restrict__ x,
    const int* __restrict__ batch, float* __restrict__ sc,
    float* __restrict__ sh, float* __restrict__ sumx,
    float* __restrict__ cntf)
{
  const int t = threadIdx.x;
  if (blockIdx.x == G_GRAPHS) {
    __shared__ float S[272];
    for (int v = t; v < 272; v += 256) {
      const float* p = gstatsT + (size_t)v * STAT_GRID;
      float s = 0.f;
      for (int bb = 0; bb < STAT_GRID; ++bb) s += p[bb];
      S[v] = s;
    }
    __syncthreads();
    if (t < 64) {
      float w[16];
#pragma unroll
      for (int j = 0; j < 16; ++j) w[j] = W1[j * 64 + t];
      const float invE = 1.0f / (float)E_EDGES;
      float mw = 0.f;
#pragma unroll
      for (int j = 0; j < 16; ++j) mw += S[256 + j] * w[j];
      mw *= invE;
      float qf = 0.f;
      for (int j = 0; j < 16; ++j) {
        float tt = 0.f;
#pragma unroll
        for (int j2 = 0; j2 < 16; ++j2) tt += S[j * 16 + j2] * w[j2];
        qf += w[j] * tt;
      }
      qf *= invE;
      float b = b1[t];
      float meanH = mw + b;
      float eh2 = qf + 2.f * b * mw + b * b;
      float var = eh2 - meanH * meanH;
      float s = gamma[t] * rsqrtf(var + 1e-5f);
      sc[t] = s;
      sh[t] = beta[t] + (b - meanH) * s;
    }
  } else {
    int g = blockIdx.x;
    __shared__ int se[2];
    if (t < 2) {
      int key = g + t;
      int lo = 0, hi = N_NODES;
      while (lo < hi) {
        int mid = (lo + hi) >> 1;
        if (batch[mid] < key) lo = mid + 1; else hi = mid;
      }
      se[t] = lo;
    }
    __syncthreads();
    int start = se[0], end = se[1];
    int c = t & 15, rr = t >> 4;
    float s = 0.f;
    for (int n = start + rr; n < end; n += 16) s += x[(size_t)n * 16 + c];
    __shared__ float red[256];
    red[t] = s;
    __syncthreads();
#pragma unroll
    for (int st = 128; st >= 16; st >>= 1) {
      if (t < st) red[t] += red[t + st];
      __syncthreads();
    }
    if (t < 16) sumx[g * 16 + t] = red[t];
    if (t == 0) cntf[g] = (float)(end - start);
  }
}

// ---------------------------------------------------------------------------
// edge_kernel: software-pipelined; per-graph accumulation via native int LDS
// atomics into per-wave fixed-point slices. 4 blocks/CU (LDS 38400B).
// ---------------------------------------------------------------------------
__global__ __launch_bounds__(256, 4) void edge_kernel(
    const unsigned* __restrict__ xh, const float* __restrict__ ea,
    const int* __restrict__ ei, const int* __restrict__ batch,
    const float* __restrict__ sc, const float* __restrict__ sh,
    const unsigned* __restrict__ Bbuf, const unsigned* __restrict__ Bw1v,
    float* __restrict__ gpart)
{
  __shared__ unsigned hh[4 * 64 * 17];    // [tile][channel][m(16) pad 17]
  __shared__ int gaccI[4][G_GRAPHS * 20]; // per-WAVE fixed-point sums
  __shared__ int gq[2][64];               // edge->graph, ping-pong
  const int tid = threadIdx.x;
  const int lane = tid & 63, wave = tid >> 6;
  const int nl = lane & 15, q = lane >> 4;
  const int* srcp = ei;
  const int* dstp = ei + E_EDGES;

  for (int v = tid; v < 4 * G_GRAPHS * 20; v += 256) ((int*)gaccI)[v] = 0;

  // persistent B fragments
  F8U bb[8][2];
#pragma unroll
  for (int sl = 0; sl < 8; ++sl)
#pragma unroll
    for (int nt = 0; nt < 2; ++nt)
      bb[sl][nt].u4 =
          ((const u32x4*)Bbuf)[((wave * 8 + sl) * 2 + nt) * 64 + lane];
  F8U bx[2];
  if (wave == 3) {
    bx[0].u4 = ((const u32x4*)Bbuf)[(32 * 2 + 0) * 64 + lane];
    bx[1].u4 = ((const u32x4*)Bbuf)[(32 * 2 + 1) * 64 + lane];
  }
  F8U bw1[4];
#pragma unroll
  for (int nt = 0; nt < 4; ++nt)
    bw1[nt].u4 = ((const u32x4*)Bw1v)[nt * 64 + lane];
  float scv[4], shv[4];
#pragma unroll
  for (int nt = 0; nt < 4; ++nt) {
    scv[nt] = sc[nt * 16 + nl];
    shv[nt] = sh[nt * 16 + nl];
  }
  const int hbase = (16 * wave + (q >> 1)) * 17 + nl;
  const int qh = q & 1;

  // ---- prologue: load iteration-0 operands ----
  int it = blockIdx.x;
  f32x4 eaA = (f32x4){0.f,0.f,0.f,0.f}, eaB = eaA;
  u32x4 xpn[4];
  {
    if (q < 2) {
      const float* p = ea + (size_t)(it * 64 + wave * 16 + nl) * 16 + q * 8;
      eaA = *(const f32x4*)p;
      eaB = *(const f32x4*)(p + 4);
    }
#pragma unroll
    for (int t = 0; t < 4; ++t) {
      int s0 = srcp[it * 64 + t * 16 + nl];
      xpn[t] = ((const u32x4*)xh)[s0 * 2 + qh];
    }
    if (wave == 0) gq[0][lane] = batch[dstp[it * 64 + lane]];
  }
  __syncthreads();  // gacc init + gq[0] visible

  int p = 0;
  for (; it < NIT; it += EDGE_GRID, p ^= 1) {
    // ---- h-stage ----
    {
      F8U aEA;
      if (q < 2) {
        aEA.h2[0] = pkrtz(eaA[0], eaA[1]); aEA.h2[1] = pkrtz(eaA[2], eaA[3]);
        aEA.h2[2] = pkrtz(eaB[0], eaB[1]); aEA.h2[3] = pkrtz(eaB[2], eaB[3]);
      } else {
        aEA.u4 = (u32x4){0u, 0u, 0u, 0u};
      }
#pragma unroll
      for (int nt = 0; nt < 4; ++nt) {
        f32x4 hD = __builtin_amdgcn_mfma_f32_16x16x32_f16(
            aEA.v, bw1[nt].v, (f32x4){0.f, 0.f, 0.f, 0.f}, 0, 0, 0);
#pragma unroll
        for (int r = 0; r < 4; ++r) {
          float h = fmaxf(hD[r] * scv[nt] + shv[nt], 0.f);
          H2U pk; pk.h = pkrtz(h, h);  // packed-duplicated
          hh[(wave * 64 + nt * 16 + nl) * 17 + q * 4 + r] = pk.u;
        }
      }
    }
    F8U xp[4];
#pragma unroll
    for (int t = 0; t < 4; ++t) xp[t].u4 = xpn[t];
    __syncthreads();  // barrier 1: hh complete

    // ---- prefetch it+EDGE_GRID (overlaps K-loop + atomics) ----
    int itn = it + EDGE_GRID;
    if (itn < NIT) {
      if (q < 2) {
        const float* pn =
            ea + (size_t)(itn * 64 + wave * 16 + nl) * 16 + q * 8;
        eaA = *(const f32x4*)pn;
        eaB = *(const f32x4*)(pn + 4);
      }
#pragma unroll
      for (int t = 0; t < 4; ++t) {
        int s1 = srcp[itn * 64 + t * 16 + nl];
        xpn[t] = ((const u32x4*)xh)[s1 * 2 + qh];
      }
      if (wave == 0) gq[p ^ 1][lane] = batch[dstp[itn * 64 + lane]];
    }

    // ---- K-loop ----
    f32x4 acc0[4], acc1[4];
#pragma unroll
    for (int t = 0; t < 4; ++t) {
      acc0[t] = (f32x4){0.f, 0.f, 0.f, 0.f};
      acc1[t] = (f32x4){0.f, 0.f, 0.f, 0.f};
    }
#pragma unroll
    for (int sl = 0; sl < 8; ++sl) {
#pragma unroll
      for (int t = 0; t < 4; ++t) {
        H2U hu; hu.u = hh[hbase + t * 1088 + sl * 34];
        F8U av;
        av.h2[0] = hu.h * xp[t].h2[0];
        av.h2[1] = hu.h * xp[t].h2[1];
        av.h2[2] = hu.h * xp[t].h2[2];
        av.h2[3] = hu.h * xp[t].h2[3];
        acc0[t] = __builtin_amdgcn_mfma_f32_16x16x32_f16(
            av.v, bb[sl][0].v, acc0[t], 0, 0, 0);
        acc1[t] = __builtin_amdgcn_mfma_f32_16x16x32_f16(
            av.v, bb[sl][1].v, acc1[t], 0, 0, 0);
      }
    }
    if (wave == 3) {  // b2 extra K-step
#pragma unroll
      for (int t = 0; t < 4; ++t) {
        F8U av;
        if (q < 2) av = xp[t];
        else       av.u4 = (u32x4){0u, 0u, 0u, 0u};
        acc0[t] = __builtin_amdgcn_mfma_f32_16x16x32_f16(
            av.v, bx[0].v, acc0[t], 0, 0, 0);
        acc1[t] = __builtin_amdgcn_mfma_f32_16x16x32_f16(
            av.v, bx[1].v, acc1[t], 0, 0, 0);
      }
    }

    // ---- fixed-point K-partials into THIS WAVE's slice (ds_add_u32) ----
    int* my = gaccI[wave];
#pragma unroll
    for (int t = 0; t < 4; ++t) {
      int rowb = t * 16 + q * 4;
#pragma unroll
      for (int r = 0; r < 4; ++r) {
        int gi = gq[p][rowb + r] * 20;
        atomicAdd(&my[gi + nl], __float2int_rn(acc0[t][r] * QSCALE));
        if (nl < 4)
          atomicAdd(&my[gi + 16 + nl], __float2int_rn(acc1[t][r] * QSCALE));
      }
    }
    __syncthreads();  // barrier 2
  }

  // ---- one flush per block: sum 4 int slices -> float gpart slice ----
  float* gp = gpart + (size_t)blockIdx.x * (G_GRAPHS * 20);
  for (int v = tid; v < G_GRAPHS * 20; v += 256)
    gp[v] = (float)(gaccI[0][v] + gaccI[1][v] + gaccI[2][v] + gaccI[3][v]) *
            QINV;
}

// ---------------------------------------------------------------------------
// critic: block per graph. Reduce gpart slices; pooled = (msgsum +
// sumx@root_w + cnt*bias)/max(cnt,1); 2-layer MLP.
// ---------------------------------------------------------------------------
__global__ __launch_bounds__(256) void critic_kernel(
    const float* __restrict__ gpart, const float* __restrict__ sumx,
    const float* __restrict__ cntf, const float* __restrict__ root_w,
    const float* __restrict__ bias, const float* __restrict__ a,
    const float* __restrict__ Wc1, const float* __restrict__ bc1,
    const float* __restrict__ Wc2, const float* __restrict__ bc2,
    float* __restrict__ out)
{
  int g = blockIdx.x, t = threadIdx.x;
  __shared__ float part[240];
  __shared__ float pooled[20];
  if (t < 240) {
    int col = t % 20, r = t / 20;  // 12 row groups
    float s = 0.f;
    for (int sl = r; sl < EDGE_GRID; sl += 12)
      s += gpart[(size_t)sl * (G_GRAPHS * 20) + g * 20 + col];
    part[t] = s;
  }
  __syncthreads();
  if (t < 20) {
    float s = 0.f;
#pragma unroll
    for (int r = 0; r < 12; ++r) s += part[r * 20 + t];
    float cnt = cntf[g];
    float base = bias[t] * cnt;
#pragma unroll
    for (int i = 0; i < 16; ++i) base += sumx[g * 16 + i] * root_w[i * 20 + t];
    pooled[t] = (s + base) / fmaxf(cnt, 1.f);
  }
  __syncthreads();
  float z = bc1[t];
#pragma unroll
  for (int j = 0; j < 20; ++j) z += pooled[j] * Wc1[j * 256 + t];
#pragma unroll
  for (int j = 0; j < 8; ++j) z += a[g * 8 + j] * Wc1[(20 + j) * 256 + t];
  z = fmaxf(z, 0.f);
  float pr = z * Wc2[t];
#pragma unroll
  for (int off = 32; off >= 1; off >>= 1) pr += __shfl_down(pr, off, 64);
  __shared__ float red[4];
  if ((t & 63) == 0) red[t >> 6] = pr;
  __syncthreads();
  if (t == 0) out[g] = red[0] + red[1] + red[2] + red[3] + bc2[0];
}

// ---------------------------------------------------------------------------
extern "C" void kernel_launch(void* const* d_in, const int* in_sizes, int n_in,
                              void* d_out, int out_size, void* d_ws,
                              size_t ws_size, hipStream_t stream) {
  const float* x         = (const float*)d_in[0];
  const float* edge_attr = (const float*)d_in[1];
  const float* a         = (const float*)d_in[2];
  const int*   ei        = (const int*)d_in[3];
  const int*   batch     = (const int*)d_in[4];
  const float* W1        = (const float*)d_in[5];
  const float* b1        = (const float*)d_in[6];
  const float* gamma     = (const float*)d_in[7];
  const float* beta      = (const float*)d_in[8];
  const float* W2        = (const float*)d_in[9];
  const float* b2        = (const float*)d_in[10];
  const float* root_w    = (const float*)d_in[11];
  const float* bias      = (const float*)d_in[12];
  const float* Wc1       = (const float*)d_in[13];
  const float* bc1       = (const float*)d_in[14];
  const float* Wc2       = (const float*)d_in[15];
  const float* bc2       = (const float*)d_in[16];
  float* out = (float*)d_out;

  // ws layout (floats) — every region fully written before read, no memset
  float* wsf     = (float*)d_ws;
  float* sc      = wsf;                 // 64
  float* sh      = wsf + 64;            // 64
  float* sumx    = wsf + 128;           // 1024
  float* cntf    = wsf + 1152;          // 64
  unsigned* Bw1  = (unsigned*)(wsf + 1216);   // 1024 u32
  unsigned* Bbuf = (unsigned*)(wsf + 2240);   // 16896 u32
  float* gstatsT = wsf + 19136;         // 272*512 = 139264
  unsigned* xhp  = (unsigned*)(wsf + 158400); // N*8 = 400000 u32
  float* gpart   = wsf + 558400;        // EDGE_GRID*1280 = 1310720

  const int XCONV_BLOCKS = (N_NODES * 8 + 255) / 256;  // 1563
  setup_kernel<<<STAT_GRID + 70 + XCONV_BLOCKS, 256, 0, stream>>>(
      W2, b2, W1, x, edge_attr, Bbuf, Bw1, xhp, gstatsT);
  mid_kernel<<<G_GRAPHS + 1, 256, 0, stream>>>(gstatsT, W1, b1, gamma, beta,
                                               x, batch, sc, sh, sumx, cntf);
  edge_kernel<<<EDGE_GRID, 256, 0, stream>>>(xhp, edge_attr, ei, batch, sc,
                                             sh, Bbuf, Bw1, gpart);
  critic_kernel<<<G_GRAPHS, 256, 0, stream>>>(gpart, sumx, cntf, root_w, bias,
                                              a, Wc1, bc1, Wc2, bc2, out);
}

// Round 7
// 263.559 us; speedup vs baseline: 1.4600x; 1.4600x over previous
//
#include <hip/hip_runtime.h>

// NNConvCritic on MI355X (gfx950).
// R7: undo R6's spill (launch_bounds(256,4) forced VGPR 64 -> 849MB scratch
// traffic). Keep grid 1024 but declare (256,2): compiler allocates ~112 VGPR
// (no spill), HW still packs 4 blocks/CU (LDS 38400x4=153.6K<160K, VGPR
// 112x16 waves < pool). gpart transposed to [g][slice][20] so critic reads
// contiguous 80KB per graph. Pipeline: setup -> mid -> edge -> critic.

#define E_EDGES   800000
#define N_NODES   50000
#define G_GRAPHS  64
#define EDGE_GRID 1024
#define STAT_GRID 512
#define NIT       (E_EDGES / 64)   // 12500
#define QSCALE    131072.0f        // 2^17
#define QINV      (1.0f / 131072.0f)

typedef _Float16 f16x2 __attribute__((ext_vector_type(2)));
typedef _Float16 f16x8 __attribute__((ext_vector_type(8)));
typedef __fp16   fp16x2 __attribute__((ext_vector_type(2)));
typedef float    f32x4 __attribute__((ext_vector_type(4)));
typedef unsigned u32x4 __attribute__((ext_vector_type(4)));

union H2U { f16x2 h; unsigned u; };
union F8U { f16x8 v; f16x2 h2[4]; u32x4 u4; };

__device__ __forceinline__ f16x2 pkrtz(float a, float b) {
  fp16x2 r = __builtin_amdgcn_cvt_pkrtz(a, b);
  return __builtin_bit_cast(f16x2, r);
}

// ---------------------------------------------------------------------------
// setup: blocks [0,512) stats | [512,582) prep | [582,...) xconv.
// ---------------------------------------------------------------------------
__global__ __launch_bounds__(256) void setup_kernel(
    const float* __restrict__ W2, const float* __restrict__ b2,
    const float* __restrict__ W1, const float* __restrict__ x,
    const float* __restrict__ ea, unsigned* __restrict__ Bbuf,
    unsigned* __restrict__ Bw1, unsigned* __restrict__ xh,
    float* __restrict__ gstatsT)
{
  __shared__ float red[4][272];
  const int b = blockIdx.x, tid = threadIdx.x;
  if (b < STAT_GRID) {
    int lane = tid & 63, wave = tid >> 6;
    int nl = lane & 15, q = lane >> 4;
    int gw = b * 4 + wave;
    f32x4 acc = (f32x4){0.f, 0.f, 0.f, 0.f};
    float ms = 0.f;
    for (int c0 = gw; c0 < E_EDGES / 32; c0 += STAT_GRID * 4) {
      const float* p = ea + (size_t)(c0 * 32 + q * 8) * 16 + nl;
      float v0 = p[0],  v1 = p[16], v2 = p[32], v3 = p[48];
      float v4 = p[64], v5 = p[80], v6 = p[96], v7 = p[112];
      ms += (v0 + v1) + (v2 + v3) + (v4 + v5) + (v6 + v7);
      F8U av;
      av.h2[0] = pkrtz(v0, v1); av.h2[1] = pkrtz(v2, v3);
      av.h2[2] = pkrtz(v4, v5); av.h2[3] = pkrtz(v6, v7);
      acc = __builtin_amdgcn_mfma_f32_16x16x32_f16(av.v, av.v, acc, 0, 0, 0);
    }
    ms += __shfl_xor(ms, 16, 64);
    ms += __shfl_xor(ms, 32, 64);
#pragma unroll
    for (int r = 0; r < 4; ++r) red[wave][(q * 4 + r) * 16 + nl] = acc[r];
    if (q == 0) red[wave][256 + nl] = ms;
    __syncthreads();
    for (int v = tid; v < 272; v += 256)
      gstatsT[(size_t)v * STAT_GRID + b] =
          red[0][v] + red[1][v] + red[2][v] + red[3][v];
  } else if (b < STAT_GRID + 70) {
    int idx = (b - STAT_GRID) * 256 + tid;  // [0, 17920) = 16896 + 1024
    if (idx < 33 * 512) {
      int r = idx & 3, lane = (idx >> 2) & 63, nt = (idx >> 8) & 1,
          s = idx >> 9;
      int q = lane >> 4, nl = lane & 15, n = nt * 16 + nl;
      float v0 = 0.f, v1 = 0.f;
      if (n < 20) {
        if (s < 32) {
          int K0 = s * 32 + q * 8 + 2 * r;
          v0 = W2[(K0 >> 4) * 320 + (K0 & 15) * 20 + n];
          v1 = W2[((K0 + 1) >> 4) * 320 + ((K0 + 1) & 15) * 20 + n];
        } else if (q < 2) {
          int i0 = q * 8 + 2 * r;
          v0 = b2[i0 * 20 + n];
          v1 = b2[(i0 + 1) * 20 + n];
        }
      }
      H2U pk; pk.h = pkrtz(v0, v1);
      Bbuf[idx] = pk.u;
    } else {
      int idx2 = idx - 33 * 512;  // [0,1024)
      int r = idx2 & 3, lane = (idx2 >> 2) & 63, nt = idx2 >> 8;
      int q = lane >> 4, nl = lane & 15, n = nt * 16 + nl;
      int k0 = q * 8 + 2 * r;
      float v0 = (k0 < 16)     ? W1[k0 * 64 + n]       : 0.f;
      float v1 = (k0 + 1 < 16) ? W1[(k0 + 1) * 64 + n] : 0.f;
      H2U pk; pk.h = pkrtz(v0, v1);
      Bw1[idx2] = pk.u;
    }
  } else {
    int i = (b - STAT_GRID - 70) * 256 + tid;
    if (i < N_NODES * 8) {
      H2U pk; pk.h = pkrtz(x[2 * i], x[2 * i + 1]);
      xh[i] = pk.u;
    }
  }
}

// ---------------------------------------------------------------------------
// mid: block 64 = stats reduce + BN scale/shift; blocks 0..63 = sumx/cnt.
// ---------------------------------------------------------------------------
__global__ __launch_bounds__(256) void mid_kernel(
    const float* __restrict__ gstatsT, const float* __restrict__ W1,
    const float* __restrict__ b1, const float* __restrict__ gamma,
    const float* __restrict__ beta, const float* __restrict__ x,
    const int* __restrict__ batch, float* __restrict__ sc,
    float* __restrict__ sh, float* __restrict__ sumx,
    float* __restrict__ cntf)
{
  const int t = threadIdx.x;
  if (blockIdx.x == G_GRAPHS) {
    __shared__ float S[272];
    for (int v = t; v < 272; v += 256) {
      const float* p = gstatsT + (size_t)v * STAT_GRID;
      float s = 0.f;
      for (int bb = 0; bb < STAT_GRID; ++bb) s += p[bb];
      S[v] = s;
    }
    __syncthreads();
    if (t < 64) {
      float w[16];
#pragma unroll
      for (int j = 0; j < 16; ++j) w[j] = W1[j * 64 + t];
      const float invE = 1.0f / (float)E_EDGES;
      float mw = 0.f;
#pragma unroll
      for (int j = 0; j < 16; ++j) mw += S[256 + j] * w[j];
      mw *= invE;
      float qf = 0.f;
      for (int j = 0; j < 16; ++j) {
        float tt = 0.f;
#pragma unroll
        for (int j2 = 0; j2 < 16; ++j2) tt += S[j * 16 + j2] * w[j2];
        qf += w[j] * tt;
      }
      qf *= invE;
      float b = b1[t];
      float meanH = mw + b;
      float eh2 = qf + 2.f * b * mw + b * b;
      float var = eh2 - meanH * meanH;
      float s = gamma[t] * rsqrtf(var + 1e-5f);
      sc[t] = s;
      sh[t] = beta[t] + (b - meanH) * s;
    }
  } else {
    int g = blockIdx.x;
    __shared__ int se[2];
    if (t < 2) {
      int key = g + t;
      int lo = 0, hi = N_NODES;
      while (lo < hi) {
        int mid = (lo + hi) >> 1;
        if (batch[mid] < key) lo = mid + 1; else hi = mid;
      }
      se[t] = lo;
    }
    __syncthreads();
    int start = se[0], end = se[1];
    int c = t & 15, rr = t >> 4;
    float s = 0.f;
    for (int n = start + rr; n < end; n += 16) s += x[(size_t)n * 16 + c];
    __shared__ float red[256];
    red[t] = s;
    __syncthreads();
#pragma unroll
    for (int st = 128; st >= 16; st >>= 1) {
      if (t < st) red[t] += red[t + st];
      __syncthreads();
    }
    if (t < 16) sumx[g * 16 + t] = red[t];
    if (t == 0) cntf[g] = (float)(end - start);
  }
}

// ---------------------------------------------------------------------------
// edge_kernel: software-pipelined; native ds_add_u32 fixed-point per-wave
// slices. grid 1024, (256,2): VGPR ~112 (no spill), HW packs 4 blocks/CU.
// gpart layout: [g][slice][20] (transposed) for coalesced critic reads.
// ---------------------------------------------------------------------------
__global__ __launch_bounds__(256, 2) void edge_kernel(
    const unsigned* __restrict__ xh, const float* __restrict__ ea,
    const int* __restrict__ ei, const int* __restrict__ batch,
    const float* __restrict__ sc, const float* __restrict__ sh,
    const unsigned* __restrict__ Bbuf, const unsigned* __restrict__ Bw1v,
    float* __restrict__ gpart)
{
  __shared__ unsigned hh[4 * 64 * 17];    // [tile][channel][m(16) pad 17]
  __shared__ int gaccI[4][G_GRAPHS * 20]; // per-WAVE fixed-point sums
  __shared__ int gq[2][64];               // edge->graph, ping-pong
  const int tid = threadIdx.x;
  const int lane = tid & 63, wave = tid >> 6;
  const int nl = lane & 15, q = lane >> 4;
  const int* srcp = ei;
  const int* dstp = ei + E_EDGES;

  for (int v = tid; v < 4 * G_GRAPHS * 20; v += 256) ((int*)gaccI)[v] = 0;

  // persistent B fragments
  F8U bb[8][2];
#pragma unroll
  for (int sl = 0; sl < 8; ++sl)
#pragma unroll
    for (int nt = 0; nt < 2; ++nt)
      bb[sl][nt].u4 =
          ((const u32x4*)Bbuf)[((wave * 8 + sl) * 2 + nt) * 64 + lane];
  F8U bx[2];
  if (wave == 3) {
    bx[0].u4 = ((const u32x4*)Bbuf)[(32 * 2 + 0) * 64 + lane];
    bx[1].u4 = ((const u32x4*)Bbuf)[(32 * 2 + 1) * 64 + lane];
  }
  F8U bw1[4];
#pragma unroll
  for (int nt = 0; nt < 4; ++nt)
    bw1[nt].u4 = ((const u32x4*)Bw1v)[nt * 64 + lane];
  float scv[4], shv[4];
#pragma unroll
  for (int nt = 0; nt < 4; ++nt) {
    scv[nt] = sc[nt * 16 + nl];
    shv[nt] = sh[nt * 16 + nl];
  }
  const int hbase = (16 * wave + (q >> 1)) * 17 + nl;
  const int qh = q & 1;

  // ---- prologue: load iteration-0 operands ----
  int it = blockIdx.x;
  f32x4 eaA = (f32x4){0.f,0.f,0.f,0.f}, eaB = eaA;
  u32x4 xpn[4];
  {
    if (q < 2) {
      const float* p = ea + (size_t)(it * 64 + wave * 16 + nl) * 16 + q * 8;
      eaA = *(const f32x4*)p;
      eaB = *(const f32x4*)(p + 4);
    }
#pragma unroll
    for (int t = 0; t < 4; ++t) {
      int s0 = srcp[it * 64 + t * 16 + nl];
      xpn[t] = ((const u32x4*)xh)[s0 * 2 + qh];
    }
    if (wave == 0) gq[0][lane] = batch[dstp[it * 64 + lane]];
  }
  __syncthreads();  // gacc init + gq[0] visible

  int p = 0;
  for (; it < NIT; it += EDGE_GRID, p ^= 1) {
    // ---- h-stage ----
    {
      F8U aEA;
      if (q < 2) {
        aEA.h2[0] = pkrtz(eaA[0], eaA[1]); aEA.h2[1] = pkrtz(eaA[2], eaA[3]);
        aEA.h2[2] = pkrtz(eaB[0], eaB[1]); aEA.h2[3] = pkrtz(eaB[2], eaB[3]);
      } else {
        aEA.u4 = (u32x4){0u, 0u, 0u, 0u};
      }
#pragma unroll
      for (int nt = 0; nt < 4; ++nt) {
        f32x4 hD = __builtin_amdgcn_mfma_f32_16x16x32_f16(
            aEA.v, bw1[nt].v, (f32x4){0.f, 0.f, 0.f, 0.f}, 0, 0, 0);
#pragma unroll
        for (int r = 0; r < 4; ++r) {
          float h = fmaxf(hD[r] * scv[nt] + shv[nt], 0.f);
          H2U pk; pk.h = pkrtz(h, h);  // packed-duplicated
          hh[(wave * 64 + nt * 16 + nl) * 17 + q * 4 + r] = pk.u;
        }
      }
    }
    F8U xp[4];
#pragma unroll
    for (int t = 0; t < 4; ++t) xp[t].u4 = xpn[t];
    __syncthreads();  // barrier 1: hh complete

    // ---- prefetch it+EDGE_GRID (overlaps K-loop + atomics) ----
    int itn = it + EDGE_GRID;
    if (itn < NIT) {
      if (q < 2) {
        const float* pn =
            ea + (size_t)(itn * 64 + wave * 16 + nl) * 16 + q * 8;
        eaA = *(const f32x4*)pn;
        eaB = *(const f32x4*)(pn + 4);
      }
#pragma unroll
      for (int t = 0; t < 4; ++t) {
        int s1 = srcp[itn * 64 + t * 16 + nl];
        xpn[t] = ((const u32x4*)xh)[s1 * 2 + qh];
      }
      if (wave == 0) gq[p ^ 1][lane] = batch[dstp[itn * 64 + lane]];
    }

    // ---- K-loop ----
    f32x4 acc0[4], acc1[4];
#pragma unroll
    for (int t = 0; t < 4; ++t) {
      acc0[t] = (f32x4){0.f, 0.f, 0.f, 0.f};
      acc1[t] = (f32x4){0.f, 0.f, 0.f, 0.f};
    }
#pragma unroll
    for (int sl = 0; sl < 8; ++sl) {
#pragma unroll
      for (int t = 0; t < 4; ++t) {
        H2U hu; hu.u = hh[hbase + t * 1088 + sl * 34];
        F8U av;
        av.h2[0] = hu.h * xp[t].h2[0];
        av.h2[1] = hu.h * xp[t].h2[1];
        av.h2[2] = hu.h * xp[t].h2[2];
        av.h2[3] = hu.h * xp[t].h2[3];
        acc0[t] = __builtin_amdgcn_mfma_f32_16x16x32_f16(
            av.v, bb[sl][0].v, acc0[t], 0, 0, 0);
        acc1[t] = __builtin_amdgcn_mfma_f32_16x16x32_f16(
            av.v, bb[sl][1].v, acc1[t], 0, 0, 0);
      }
    }
    if (wave == 3) {  // b2 extra K-step
#pragma unroll
      for (int t = 0; t < 4; ++t) {
        F8U av;
        if (q < 2) av = xp[t];
        else       av.u4 = (u32x4){0u, 0u, 0u, 0u};
        acc0[t] = __builtin_amdgcn_mfma_f32_16x16x32_f16(
            av.v, bx[0].v, acc0[t], 0, 0, 0);
        acc1[t] = __builtin_amdgcn_mfma_f32_16x16x32_f16(
            av.v, bx[1].v, acc1[t], 0, 0, 0);
      }
    }

    // ---- fixed-point K-partials into THIS WAVE's slice (ds_add_u32) ----
    int* my = gaccI[wave];
#pragma unroll
    for (int t = 0; t < 4; ++t) {
      int rowb = t * 16 + q * 4;
#pragma unroll
      for (int r = 0; r < 4; ++r) {
        int gi = gq[p][rowb + r] * 20;
        atomicAdd(&my[gi + nl], __float2int_rn(acc0[t][r] * QSCALE));
        if (nl < 4)
          atomicAdd(&my[gi + 16 + nl], __float2int_rn(acc1[t][r] * QSCALE));
      }
    }
    __syncthreads();  // barrier 2
  }

  // ---- flush: transposed gpart [g][slice][20] ----
  for (int v = tid; v < G_GRAPHS * 20; v += 256) {
    int g = v / 20, o = v - g * 20;
    float s = (float)(gaccI[0][v] + gaccI[1][v] + gaccI[2][v] + gaccI[3][v]) *
              QINV;
    gpart[((size_t)g * EDGE_GRID + blockIdx.x) * 20 + o] = s;
  }
}

// ---------------------------------------------------------------------------
// critic: block per graph. Contiguous 80KB gpart scan per graph; pooled =
// (msgsum + sumx@root_w + cnt*bias)/max(cnt,1); 2-layer MLP.
// ---------------------------------------------------------------------------
__global__ __launch_bounds__(256) void critic_kernel(
    const float* __restrict__ gpart, const float* __restrict__ sumx,
    const float* __restrict__ cntf, const float* __restrict__ root_w,
    const float* __restrict__ bias, const float* __restrict__ a,
    const float* __restrict__ Wc1, const float* __restrict__ bc1,
    const float* __restrict__ Wc2, const float* __restrict__ bc2,
    float* __restrict__ out)
{
  int g = blockIdx.x, t = threadIdx.x;
  __shared__ float part[240];
  __shared__ float pooled[20];
  if (t < 240) {
    int col = t % 20, r = t / 20;  // 12 slice groups
    float s = 0.f;
    const float* gp = gpart + (size_t)g * EDGE_GRID * 20;
    for (int sl = r; sl < EDGE_GRID; sl += 12) s += gp[sl * 20 + col];
    part[t] = s;
  }
  __syncthreads();
  if (t < 20) {
    float s = 0.f;
#pragma unroll
    for (int r = 0; r < 12; ++r) s += part[r * 20 + t];
    float cnt = cntf[g];
    float base = bias[t] * cnt;
#pragma unroll
    for (int i = 0; i < 16; ++i) base += sumx[g * 16 + i] * root_w[i * 20 + t];
    pooled[t] = (s + base) / fmaxf(cnt, 1.f);
  }
  __syncthreads();
  float z = bc1[t];
#pragma unroll
  for (int j = 0; j < 20; ++j) z += pooled[j] * Wc1[j * 256 + t];
#pragma unroll
  for (int j = 0; j < 8; ++j) z += a[g * 8 + j] * Wc1[(20 + j) * 256 + t];
  z = fmaxf(z, 0.f);
  float pr = z * Wc2[t];
#pragma unroll
  for (int off = 32; off >= 1; off >>= 1) pr += __shfl_down(pr, off, 64);
  __shared__ float red[4];
  if ((t & 63) == 0) red[t >> 6] = pr;
  __syncthreads();
  if (t == 0) out[g] = red[0] + red[1] + red[2] + red[3] + bc2[0];
}

// ---------------------------------------------------------------------------
extern "C" void kernel_launch(void* const* d_in, const int* in_sizes, int n_in,
                              void* d_out, int out_size, void* d_ws,
                              size_t ws_size, hipStream_t stream) {
  const float* x         = (const float*)d_in[0];
  const float* edge_attr = (const float*)d_in[1];
  const float* a         = (const float*)d_in[2];
  const int*   ei        = (const int*)d_in[3];
  const int*   batch     = (const int*)d_in[4];
  const float* W1        = (const float*)d_in[5];
  const float* b1        = (const float*)d_in[6];
  const float* gamma     = (const float*)d_in[7];
  const float* beta      = (const float*)d_in[8];
  const float* W2        = (const float*)d_in[9];
  const float* b2        = (const float*)d_in[10];
  const float* root_w    = (const float*)d_in[11];
  const float* bias      = (const float*)d_in[12];
  const float* Wc1       = (const float*)d_in[13];
  const float* bc1       = (const float*)d_in[14];
  const float* Wc2       = (const float*)d_in[15];
  const float* bc2       = (const float*)d_in[16];
  float* out = (float*)d_out;

  // ws layout (floats) — every region fully written before read, no memset
  float* wsf     = (float*)d_ws;
  float* sc      = wsf;                 // 64
  float* sh      = wsf + 64;            // 64
  float* sumx    = wsf + 128;           // 1024
  float* cntf    = wsf + 1152;          // 64
  unsigned* Bw1  = (unsigned*)(wsf + 1216);   // 1024 u32
  unsigned* Bbuf = (unsigned*)(wsf + 2240);   // 16896 u32
  float* gstatsT = wsf + 19136;         // 272*512 = 139264
  unsigned* xhp  = (unsigned*)(wsf + 158400); // N*8 = 400000 u32
  float* gpart   = wsf + 558400;        // G*EDGE_GRID*20 = 1310720

  const int XCONV_BLOCKS = (N_NODES * 8 + 255) / 256;  // 1563
  setup_kernel<<<STAT_GRID + 70 + XCONV_BLOCKS, 256, 0, stream>>>(
      W2, b2, W1, x, edge_attr, Bbuf, Bw1, xhp, gstatsT);
  mid_kernel<<<G_GRAPHS + 1, 256, 0, stream>>>(gstatsT, W1, b1, gamma, beta,
                                               x, batch, sc, sh, sumx, cntf);
  edge_kernel<<<EDGE_GRID, 256, 0, stream>>>(xhp, edge_attr, ei, batch, sc,
                                             sh, Bbuf, Bw1, gpart);
  critic_kernel<<<G_GRAPHS, 256, 0, stream>>>(gpart, sumx, cntf, root_w, bias,
                                              a, Wc1, bc1, Wc2, bc2, out);
}

// Round 8
// 251.422 us; speedup vs baseline: 1.5305x; 1.0483x over previous
//
#include <hip/hip_runtime.h>

// NNConvCritic on MI355X (gfx950).
// R8: wave-autonomous edge kernel. (edge-group x K-quarter) units are
// linearly independent -> 64-thread blocks, one kq stream each, private LDS
// h-buffer + private gacc, ZERO barriers in the loop (R5/R7 evidence:
// 10.3K cyc/iter lockstep latency invariant to grid size). kq partners
// mapped to same XCD (blockIdx%8) so 4x ea re-reads hit L2/L3 not HBM.
// Flush: per-block int sums -> global int atomicAdd into 256 super-slices
// (12 adds/addr). Pipeline: memset+setup -> mid -> edge -> critic.

#define E_EDGES   800000
#define N_NODES   50000
#define G_GRAPHS  64
#define EDGE_GRID 3072      // 3072 single-wave blocks = 12/CU at 3 waves/SIMD
#define NGROUPS   50000     // E/16
#define GSTRIDE   768       // groups advance per iteration (3072/4)
#define NSUP      256       // super-slices for the int flush
#define STAT_GRID 512
#define QSCALE    131072.0f // 2^17
#define QINV      (1.0f / 131072.0f)

typedef _Float16 f16x2 __attribute__((ext_vector_type(2)));
typedef _Float16 f16x8 __attribute__((ext_vector_type(8)));
typedef __fp16   fp16x2 __attribute__((ext_vector_type(2)));
typedef float    f32x4 __attribute__((ext_vector_type(4)));
typedef unsigned u32x4 __attribute__((ext_vector_type(4)));

union H2U { f16x2 h; unsigned u; };
union F8U { f16x8 v; f16x2 h2[4]; u32x4 u4; };

__device__ __forceinline__ f16x2 pkrtz(float a, float b) {
  fp16x2 r = __builtin_amdgcn_cvt_pkrtz(a, b);
  return __builtin_bit_cast(f16x2, r);
}

// ---------------------------------------------------------------------------
// setup: blocks [0,512) stats | [512,582) prep | [582,...) xconv.
// ---------------------------------------------------------------------------
__global__ __launch_bounds__(256) void setup_kernel(
    const float* __restrict__ W2, const float* __restrict__ b2,
    const float* __restrict__ W1, const float* __restrict__ x,
    const float* __restrict__ ea, unsigned* __restrict__ Bbuf,
    unsigned* __restrict__ Bw1, unsigned* __restrict__ xh,
    float* __restrict__ gstatsT)
{
  __shared__ float red[4][272];
  const int b = blockIdx.x, tid = threadIdx.x;
  if (b < STAT_GRID) {
    int lane = tid & 63, wave = tid >> 6;
    int nl = lane & 15, q = lane >> 4;
    int gw = b * 4 + wave;
    f32x4 acc = (f32x4){0.f, 0.f, 0.f, 0.f};
    float ms = 0.f;
    for (int c0 = gw; c0 < E_EDGES / 32; c0 += STAT_GRID * 4) {
      const float* p = ea + (size_t)(c0 * 32 + q * 8) * 16 + nl;
      float v0 = p[0],  v1 = p[16], v2 = p[32], v3 = p[48];
      float v4 = p[64], v5 = p[80], v6 = p[96], v7 = p[112];
      ms += (v0 + v1) + (v2 + v3) + (v4 + v5) + (v6 + v7);
      F8U av;
      av.h2[0] = pkrtz(v0, v1); av.h2[1] = pkrtz(v2, v3);
      av.h2[2] = pkrtz(v4, v5); av.h2[3] = pkrtz(v6, v7);
      acc = __builtin_amdgcn_mfma_f32_16x16x32_f16(av.v, av.v, acc, 0, 0, 0);
    }
    ms += __shfl_xor(ms, 16, 64);
    ms += __shfl_xor(ms, 32, 64);
#pragma unroll
    for (int r = 0; r < 4; ++r) red[wave][(q * 4 + r) * 16 + nl] = acc[r];
    if (q == 0) red[wave][256 + nl] = ms;
    __syncthreads();
    for (int v = tid; v < 272; v += 256)
      gstatsT[(size_t)v * STAT_GRID + b] =
          red[0][v] + red[1][v] + red[2][v] + red[3][v];
  } else if (b < STAT_GRID + 70) {
    int idx = (b - STAT_GRID) * 256 + tid;  // [0, 17920) = 16896 + 1024
    if (idx < 33 * 512) {
      int r = idx & 3, lane = (idx >> 2) & 63, nt = (idx >> 8) & 1,
          s = idx >> 9;
      int q = lane >> 4, nl = lane & 15, n = nt * 16 + nl;
      float v0 = 0.f, v1 = 0.f;
      if (n < 20) {
        if (s < 32) {
          int K0 = s * 32 + q * 8 + 2 * r;
          v0 = W2[(K0 >> 4) * 320 + (K0 & 15) * 20 + n];
          v1 = W2[((K0 + 1) >> 4) * 320 + ((K0 + 1) & 15) * 20 + n];
        } else if (q < 2) {
          int i0 = q * 8 + 2 * r;
          v0 = b2[i0 * 20 + n];
          v1 = b2[(i0 + 1) * 20 + n];
        }
      }
      H2U pk; pk.h = pkrtz(v0, v1);
      Bbuf[idx] = pk.u;
    } else {
      int idx2 = idx - 33 * 512;  // [0,1024)
      int r = idx2 & 3, lane = (idx2 >> 2) & 63, nt = idx2 >> 8;
      int q = lane >> 4, nl = lane & 15, n = nt * 16 + nl;
      int k0 = q * 8 + 2 * r;
      float v0 = (k0 < 16)     ? W1[k0 * 64 + n]       : 0.f;
      float v1 = (k0 + 1 < 16) ? W1[(k0 + 1) * 64 + n] : 0.f;
      H2U pk; pk.h = pkrtz(v0, v1);
      Bw1[idx2] = pk.u;
    }
  } else {
    int i = (b - STAT_GRID - 70) * 256 + tid;
    if (i < N_NODES * 8) {
      H2U pk; pk.h = pkrtz(x[2 * i], x[2 * i + 1]);
      xh[i] = pk.u;
    }
  }
}

// ---------------------------------------------------------------------------
// mid: block 64 = stats reduce + BN scale/shift; blocks 0..63 = sumx/cnt.
// ---------------------------------------------------------------------------
__global__ __launch_bounds__(256) void mid_kernel(
    const float* __restrict__ gstatsT, const float* __restrict__ W1,
    const float* __restrict__ b1, const float* __restrict__ gamma,
    const float* __restrict__ beta, const float* __restrict__ x,
    const int* __restrict__ batch, float* __restrict__ sc,
    float* __restrict__ sh, float* __restrict__ sumx,
    float* __restrict__ cntf)
{
  const int t = threadIdx.x;
  if (blockIdx.x == G_GRAPHS) {
    __shared__ float S[272];
    for (int v = t; v < 272; v += 256) {
      const float* p = gstatsT + (size_t)v * STAT_GRID;
      float s = 0.f;
      for (int bb = 0; bb < STAT_GRID; ++bb) s += p[bb];
      S[v] = s;
    }
    __syncthreads();
    if (t < 64) {
      float w[16];
#pragma unroll
      for (int j = 0; j < 16; ++j) w[j] = W1[j * 64 + t];
      const float invE = 1.0f / (float)E_EDGES;
      float mw = 0.f;
#pragma unroll
      for (int j = 0; j < 16; ++j) mw += S[256 + j] * w[j];
      mw *= invE;
      float qf = 0.f;
      for (int j = 0; j < 16; ++j) {
        float tt = 0.f;
#pragma unroll
        for (int j2 = 0; j2 < 16; ++j2) tt += S[j * 16 + j2] * w[j2];
        qf += w[j] * tt;
      }
      qf *= invE;
      float b = b1[t];
      float meanH = mw + b;
      float eh2 = qf + 2.f * b * mw + b * b;
      float var = eh2 - meanH * meanH;
      float s = gamma[t] * rsqrtf(var + 1e-5f);
      sc[t] = s;
      sh[t] = beta[t] + (b - meanH) * s;
    }
  } else {
    int g = blockIdx.x;
    __shared__ int se[2];
    if (t < 2) {
      int key = g + t;
      int lo = 0, hi = N_NODES;
      while (lo < hi) {
        int mid = (lo + hi) >> 1;
        if (batch[mid] < key) lo = mid + 1; else hi = mid;
      }
      se[t] = lo;
    }
    __syncthreads();
    int start = se[0], end = se[1];
    int c = t & 15, rr = t >> 4;
    float s = 0.f;
    for (int n = start + rr; n < end; n += 16) s += x[(size_t)n * 16 + c];
    __shared__ float red[256];
    red[t] = s;
    __syncthreads();
#pragma unroll
    for (int st = 128; st >= 16; st >>= 1) {
      if (t < st) red[t] += red[t + st];
      __syncthreads();
    }
    if (t < 16) sumx[g * 16 + t] = red[t];
    if (t == 0) cntf[g] = (float)(end - start);
  }
}

// ---------------------------------------------------------------------------
// edge_kernel: one wave per block, barrier-free. Stream s handles K-quarter
// kq=(s>>3)&3 of groups sgroup, sgroup+768, ... (kq partners differ by 8 ->
// same XCD -> ea re-reads hit L2/L3). Private hh (h transpose) + private
// gacc (ds_add_u32 fixed point). Flush: global int atomics into super-slices.
// ---------------------------------------------------------------------------
__global__ __launch_bounds__(64, 3) void edge_kernel(
    const unsigned* __restrict__ xh, const float* __restrict__ ea,
    const int* __restrict__ ei, const int* __restrict__ batch,
    const float* __restrict__ sc, const float* __restrict__ sh,
    const unsigned* __restrict__ Bbuf, const unsigned* __restrict__ Bw1v,
    int* __restrict__ gpartI)
{
  __shared__ unsigned hh[320];   // [channel 16][m 16 pad 20]
  __shared__ int gacc[1280];     // per-graph fixed-point sums (this wave)
  const int lane = threadIdx.x;
  const int nl = lane & 15, q = lane >> 4;
  const int s = blockIdx.x;
  const int kq = (s >> 3) & 3;
  const int sgroup = ((s >> 5) << 3) | (s & 7);   // [0, 768)
  const int* srcp = ei;
  const int* dstp = ei + E_EDGES;

  for (int v = lane; v < 1280; v += 64) gacc[v] = 0;

  // persistent B fragments (this wave's K-quarter)
  F8U bb[8][2];
#pragma unroll
  for (int sl = 0; sl < 8; ++sl)
#pragma unroll
    for (int nt = 0; nt < 2; ++nt)
      bb[sl][nt].u4 =
          ((const u32x4*)Bbuf)[((kq * 8 + sl) * 2 + nt) * 64 + lane];
  F8U bx[2];
  if (kq == 3) {
    bx[0].u4 = ((const u32x4*)Bbuf)[64 * 64 + lane];
    bx[1].u4 = ((const u32x4*)Bbuf)[65 * 64 + lane];
  } else {
    bx[0].u4 = (u32x4){0u, 0u, 0u, 0u};
    bx[1].u4 = (u32x4){0u, 0u, 0u, 0u};
  }
  F8U bw1; bw1.u4 = ((const u32x4*)Bw1v)[kq * 64 + lane];
  const float scv = sc[kq * 16 + nl];
  const float shv = sh[kq * 16 + nl];
  const int hrb = (q >> 1) * 20 + nl;   // read base: c = 2sl + (q>>1), m = nl
  const int qh = q & 1;

  // ---- prologue: loads for first group ----
  int g = sgroup;
  f32x4 eaA = (f32x4){0.f,0.f,0.f,0.f}, eaB = eaA;
  u32x4 xp = (u32x4){0u,0u,0u,0u};
  int gq0 = 0, gq1 = 0, gq2 = 0, gq3 = 0;
  {
    int base = g * 16;
    if (q < 2) {
      const float* p = ea + (size_t)(base + nl) * 16 + q * 8;
      eaA = *(const f32x4*)p;
      eaB = *(const f32x4*)(p + 4);
    }
    int src = srcp[base + nl];
    xp = ((const u32x4*)xh)[src * 2 + qh];
    gq0 = batch[dstp[base + q * 4 + 0]];
    gq1 = batch[dstp[base + q * 4 + 1]];
    gq2 = batch[dstp[base + q * 4 + 2]];
    gq3 = batch[dstp[base + q * 4 + 3]];
  }

  while (g < NGROUPS) {
    const int gn = g + GSTRIDE;

    // ---- h-stage: 16 edges x this wave's 16 channels (1 MFMA) ----
    {
      F8U aEA;
      if (q < 2) {
        aEA.h2[0] = pkrtz(eaA[0], eaA[1]); aEA.h2[1] = pkrtz(eaA[2], eaA[3]);
        aEA.h2[2] = pkrtz(eaB[0], eaB[1]); aEA.h2[3] = pkrtz(eaB[2], eaB[3]);
      } else {
        aEA.u4 = (u32x4){0u, 0u, 0u, 0u};
      }
      f32x4 hD = __builtin_amdgcn_mfma_f32_16x16x32_f16(
          aEA.v, bw1.v, (f32x4){0.f, 0.f, 0.f, 0.f}, 0, 0, 0);
#pragma unroll
      for (int r = 0; r < 4; ++r) {
        float h = fmaxf(hD[r] * scv + shv, 0.f);
        H2U pk; pk.h = pkrtz(h, h);   // packed-duplicated
        hh[nl * 20 + q * 4 + r] = pk.u;   // [c=nl][m=q*4+r], b128-mergeable
      }
    }
    F8U xcur; xcur.u4 = xp;

    // ---- prefetch next group (overlaps K-loop; wave-local vmcnt) ----
    f32x4 eaAn = (f32x4){0.f,0.f,0.f,0.f}, eaBn = eaAn;
    u32x4 xpn = (u32x4){0u,0u,0u,0u};
    int gq0n = 0, gq1n = 0, gq2n = 0, gq3n = 0;
    if (gn < NGROUPS) {
      int base = gn * 16;
      if (q < 2) {
        const float* p = ea + (size_t)(base + nl) * 16 + q * 8;
        eaAn = *(const f32x4*)p;
        eaBn = *(const f32x4*)(p + 4);
      }
      int src = srcp[base + nl];
      xpn = ((const u32x4*)xh)[src * 2 + qh];
      gq0n = batch[dstp[base + q * 4 + 0]];
      gq1n = batch[dstp[base + q * 4 + 1]];
      gq2n = batch[dstp[base + q * 4 + 2]];
      gq3n = batch[dstp[base + q * 4 + 3]];
    }

    // ---- K-loop: A[m][k] = h[m][c] * x[m][i], 8 steps x 2 N-tiles ----
    f32x4 acc0 = (f32x4){0.f, 0.f, 0.f, 0.f};
    f32x4 acc1 = (f32x4){0.f, 0.f, 0.f, 0.f};
#pragma unroll
    for (int sl = 0; sl < 8; ++sl) {
      H2U hu; hu.u = hh[hrb + sl * 40];
      F8U av;
      av.h2[0] = hu.h * xcur.h2[0];
      av.h2[1] = hu.h * xcur.h2[1];
      av.h2[2] = hu.h * xcur.h2[2];
      av.h2[3] = hu.h * xcur.h2[3];
      acc0 = __builtin_amdgcn_mfma_f32_16x16x32_f16(av.v, bb[sl][0].v, acc0,
                                                    0, 0, 0);
      acc1 = __builtin_amdgcn_mfma_f32_16x16x32_f16(av.v, bb[sl][1].v, acc1,
                                                    0, 0, 0);
    }
    if (kq == 3) {   // b2 extra K-step: A = x (coefficient-1 trick)
      F8U av;
      if (q < 2) av = xcur;
      else       av.u4 = (u32x4){0u, 0u, 0u, 0u};
      acc0 = __builtin_amdgcn_mfma_f32_16x16x32_f16(av.v, bx[0].v, acc0,
                                                    0, 0, 0);
      acc1 = __builtin_amdgcn_mfma_f32_16x16x32_f16(av.v, bx[1].v, acc1,
                                                    0, 0, 0);
    }

    // ---- fixed-point partials into private gacc (native ds_add_u32) ----
    {
      int gi;
      gi = gq0 * 20;
      atomicAdd(&gacc[gi + nl], __float2int_rn(acc0[0] * QSCALE));
      if (nl < 4) atomicAdd(&gacc[gi + 16 + nl], __float2int_rn(acc1[0] * QSCALE));
      gi = gq1 * 20;
      atomicAdd(&gacc[gi + nl], __float2int_rn(acc0[1] * QSCALE));
      if (nl < 4) atomicAdd(&gacc[gi + 16 + nl], __float2int_rn(acc1[1] * QSCALE));
      gi = gq2 * 20;
      atomicAdd(&gacc[gi + nl], __float2int_rn(acc0[2] * QSCALE));
      if (nl < 4) atomicAdd(&gacc[gi + 16 + nl], __float2int_rn(acc1[2] * QSCALE));
      gi = gq3 * 20;
      atomicAdd(&gacc[gi + nl], __float2int_rn(acc0[3] * QSCALE));
      if (nl < 4) atomicAdd(&gacc[gi + 16 + nl], __float2int_rn(acc1[3] * QSCALE));
    }

    // rotate prefetch -> current
    g = gn;
    eaA = eaAn; eaB = eaBn; xp = xpn;
    gq0 = gq0n; gq1 = gq1n; gq2 = gq2n; gq3 = gq3n;
  }

  // ---- flush: global int atomics into super-slice (12 blocks/slice) ----
  const int ssup = s & (NSUP - 1);
  for (int v = lane; v < 1280; v += 64) {
    int gg = v / 20, o = v - gg * 20;
    atomicAdd(&gpartI[(gg * NSUP + ssup) * 20 + o], gacc[v]);
  }
}

// ---------------------------------------------------------------------------
// critic: block per graph. Exact int reduce of 256 super-slices; pooled =
// (msgsum + sumx@root_w + cnt*bias)/max(cnt,1); 2-layer MLP.
// ---------------------------------------------------------------------------
__global__ __launch_bounds__(256) void critic_kernel(
    const int* __restrict__ gpartI, const float* __restrict__ sumx,
    const float* __restrict__ cntf, const float* __restrict__ root_w,
    const float* __restrict__ bias, const float* __restrict__ a,
    const float* __restrict__ Wc1, const float* __restrict__ bc1,
    const float* __restrict__ Wc2, const float* __restrict__ bc2,
    float* __restrict__ out)
{
  int g = blockIdx.x, t = threadIdx.x;
  __shared__ int part[240];
  __shared__ float pooled[20];
  if (t < 240) {
    int col = t % 20, r = t / 20;  // 12 slice groups
    int s = 0;
    const int* gp = gpartI + (size_t)g * NSUP * 20;
    for (int sl = r; sl < NSUP; sl += 12) s += gp[sl * 20 + col];
    part[t] = s;
  }
  __syncthreads();
  if (t < 20) {
    int si = 0;
#pragma unroll
    for (int r = 0; r < 12; ++r) si += part[r * 20 + t];
    float s = (float)si * QINV;
    float cnt = cntf[g];
    float base = bias[t] * cnt;
#pragma unroll
    for (int i = 0; i < 16; ++i) base += sumx[g * 16 + i] * root_w[i * 20 + t];
    pooled[t] = (s + base) / fmaxf(cnt, 1.f);
  }
  __syncthreads();
  float z = bc1[t];
#pragma unroll
  for (int j = 0; j < 20; ++j) z += pooled[j] * Wc1[j * 256 + t];
#pragma unroll
  for (int j = 0; j < 8; ++j) z += a[g * 8 + j] * Wc1[(20 + j) * 256 + t];
  z = fmaxf(z, 0.f);
  float pr = z * Wc2[t];
#pragma unroll
  for (int off = 32; off >= 1; off >>= 1) pr += __shfl_down(pr, off, 64);
  __shared__ float red[4];
  if ((t & 63) == 0) red[t >> 6] = pr;
  __syncthreads();
  if (t == 0) out[g] = red[0] + red[1] + red[2] + red[3] + bc2[0];
}

// ---------------------------------------------------------------------------
extern "C" void kernel_launch(void* const* d_in, const int* in_sizes, int n_in,
                              void* d_out, int out_size, void* d_ws,
                              size_t ws_size, hipStream_t stream) {
  const float* x         = (const float*)d_in[0];
  const float* edge_attr = (const float*)d_in[1];
  const float* a         = (const float*)d_in[2];
  const int*   ei        = (const int*)d_in[3];
  const int*   batch     = (const int*)d_in[4];
  const float* W1        = (const float*)d_in[5];
  const float* b1        = (const float*)d_in[6];
  const float* gamma     = (const float*)d_in[7];
  const float* beta      = (const float*)d_in[8];
  const float* W2        = (const float*)d_in[9];
  const float* b2        = (const float*)d_in[10];
  const float* root_w    = (const float*)d_in[11];
  const float* bias      = (const float*)d_in[12];
  const float* Wc1       = (const float*)d_in[13];
  const float* bc1       = (const float*)d_in[14];
  const float* Wc2       = (const float*)d_in[15];
  const float* bc2       = (const float*)d_in[16];
  float* out = (float*)d_out;

  // ws layout (floats) — gpartI zeroed via memset, rest fully written
  float* wsf     = (float*)d_ws;
  float* sc      = wsf;                 // 64
  float* sh      = wsf + 64;            // 64
  float* sumx    = wsf + 128;           // 1024
  float* cntf    = wsf + 1152;          // 64
  unsigned* Bw1  = (unsigned*)(wsf + 1216);   // 1024 u32
  unsigned* Bbuf = (unsigned*)(wsf + 2240);   // 16896 u32
  float* gstatsT = wsf + 19136;         // 272*512 = 139264
  unsigned* xhp  = (unsigned*)(wsf + 158400); // N*8 = 400000 u32
  int* gpartI    = (int*)(wsf + 558400);      // 64*256*20 = 327680 ints

  (void)hipMemsetAsync(gpartI, 0, (size_t)G_GRAPHS * NSUP * 20 * sizeof(int),
                       stream);

  const int XCONV_BLOCKS = (N_NODES * 8 + 255) / 256;  // 1563
  setup_kernel<<<STAT_GRID + 70 + XCONV_BLOCKS, 256, 0, stream>>>(
      W2, b2, W1, x, edge_attr, Bbuf, Bw1, xhp, gstatsT);
  mid_kernel<<<G_GRAPHS + 1, 256, 0, stream>>>(gstatsT, W1, b1, gamma, beta,
                                               x, batch, sc, sh, sumx, cntf);
  edge_kernel<<<EDGE_GRID, 64, 0, stream>>>(xhp, edge_attr, ei, batch, sc,
                                            sh, Bbuf, Bw1, gpartI);
  critic_kernel<<<G_GRAPHS, 256, 0, stream>>>(gpartI, sumx, cntf, root_w,
                                              bias, a, Wc1, bc1, Wc2, bc2,
                                              out);
}